// Round 1
// baseline (1507.866 us; speedup 1.0000x reference)
//
#include <hip/hip_runtime.h>
#include <hip/hip_bf16.h>

typedef __attribute__((ext_vector_type(8))) short short8;
typedef __attribute__((ext_vector_type(4))) float f32x4;

__device__ __forceinline__ unsigned short f2bf(float f) {
    __hip_bfloat16 h = __float2bfloat16(f);
    union { __hip_bfloat16 h; unsigned short u; } c; c.h = h; return c.u;
}
__device__ __forceinline__ float bf2f(unsigned short u) {
    union { unsigned int i; float f; } c; c.i = ((unsigned int)u) << 16; return c.f;
}

// ---------------------------------------------------------------- bias expand
// bias_full[h*9604 + n*98 + m] = bias_table[rel_index[n*98+m]*8 + h]
__global__ void bias_expand_kernel(const float* __restrict__ bias_table,
                                   const int* __restrict__ rel_index,
                                   float* __restrict__ bias_full) {
    int idx = blockIdx.x * 256 + threadIdx.x;
    if (idx >= 8 * 9604) return;
    int h = idx / 9604;
    int r = idx - h * 9604;
    bias_full[idx] = bias_table[rel_index[r] * 8 + h];
}

// ---------------------------------------------------------------- QKV GEMM
// C[m][c3] = sum_k X[m][k] * W[c3][k] + b[c3], scattered to q/k/v (b,h,n,d) bf16
#define LDSK 72  // 64 + 8 pad (bf16) -> 144B row stride, 2-way bank alias (free)

__global__ __launch_bounds__(256, 2)
void gemm_qkv_kernel(const float* __restrict__ X,
                     const float* __restrict__ W,
                     const float* __restrict__ bias,
                     unsigned short* __restrict__ qws,
                     unsigned short* __restrict__ kws,
                     unsigned short* __restrict__ vws) {
    __shared__ unsigned short As[128 * LDSK];
    __shared__ unsigned short Bs[128 * LDSK];
    const int tid = threadIdx.x;
    const int wave = tid >> 6, lane = tid & 63;
    const int q4 = lane >> 4, l16 = lane & 15;
    const int wr = wave >> 1, wc = wave & 1;
    const long m0 = (long)blockIdx.y * 128;
    const int n0 = blockIdx.x * 128;

    f32x4 acc[4][4];
#pragma unroll
    for (int i = 0; i < 4; ++i)
#pragma unroll
        for (int j = 0; j < 4; ++j) acc[i][j] = (f32x4){0.f, 0.f, 0.f, 0.f};

    for (int ks = 0; ks < 256; ks += 64) {
#pragma unroll
        for (int it = 0; it < 8; ++it) {
            int e = (it * 256 + tid) * 4;
            int m = e >> 6, k = e & 63;
            float4 f = *reinterpret_cast<const float4*>(X + (m0 + m) * 256 + ks + k);
            unsigned int lo = ((unsigned)f2bf(f.y) << 16) | f2bf(f.x);
            unsigned int hi = ((unsigned)f2bf(f.w) << 16) | f2bf(f.z);
            *reinterpret_cast<uint2*>(&As[m * LDSK + k]) = make_uint2(lo, hi);
        }
#pragma unroll
        for (int it = 0; it < 8; ++it) {
            int e = (it * 256 + tid) * 4;
            int n = e >> 6, k = e & 63;
            float4 f = *reinterpret_cast<const float4*>(W + (long)(n0 + n) * 256 + ks + k);
            unsigned int lo = ((unsigned)f2bf(f.y) << 16) | f2bf(f.x);
            unsigned int hi = ((unsigned)f2bf(f.w) << 16) | f2bf(f.z);
            *reinterpret_cast<uint2*>(&Bs[n * LDSK + k]) = make_uint2(lo, hi);
        }
        __syncthreads();
#pragma unroll
        for (int s = 0; s < 2; ++s) {
            short8 a[4], b[4];
#pragma unroll
            for (int i = 0; i < 4; ++i)
                a[i] = *reinterpret_cast<const short8*>(&As[(wr * 64 + i * 16 + l16) * LDSK + s * 32 + q4 * 8]);
#pragma unroll
            for (int j = 0; j < 4; ++j)
                b[j] = *reinterpret_cast<const short8*>(&Bs[(wc * 64 + j * 16 + l16) * LDSK + s * 32 + q4 * 8]);
#pragma unroll
            for (int i = 0; i < 4; ++i)
#pragma unroll
                for (int j = 0; j < 4; ++j)
                    acc[i][j] = __builtin_amdgcn_mfma_f32_16x16x32_bf16(a[i], b[j], acc[i][j], 0, 0, 0);
        }
        __syncthreads();
    }
    // epilogue: scatter per-head
#pragma unroll
    for (int i = 0; i < 4; ++i) {
#pragma unroll
        for (int r = 0; r < 4; ++r) {
            long row = m0 + wr * 64 + i * 16 + q4 * 4 + r;
            int b_ = (int)(row / 98);
            int n_ = (int)(row - (long)b_ * 98);
#pragma unroll
            for (int j = 0; j < 4; ++j) {
                int col = n0 + wc * 64 + j * 16 + l16;
                float v = acc[i][j][r] + bias[col];
                int which = col >> 8;
                int h = (col >> 5) & 7;
                int d = col & 31;
                unsigned short* dst = (which == 0) ? qws : ((which == 1) ? kws : vws);
                dst[((long)(b_ * 8 + h) * 98 + n_) * 32 + d] = f2bf(v);
            }
        }
    }
}

// ---------------------------------------------------------------- attention
// one block (256 thr) per (b,h). S kept in registers per wave row-band.
__global__ __launch_bounds__(256, 2)
void attn_kernel(const unsigned short* __restrict__ q,
                 const unsigned short* __restrict__ k,
                 const unsigned short* __restrict__ v,
                 const float* __restrict__ mask,       // (512,98,98)
                 const float* __restrict__ bias_full,  // (8,98,98)
                 unsigned short* __restrict__ attn_out) {
    __shared__ unsigned short Qs[112 * 40];   // stride 40 bf16 = 80B
    __shared__ unsigned short Ks[112 * 40];
    __shared__ unsigned short Vt[32 * 136];   // V^T [d][m], stride 136 bf16
    __shared__ unsigned short P[112 * 136];   // P [n][m], stride 136 bf16

    const int tid = threadIdx.x;
    const int wave = tid >> 6, lane = tid & 63;
    const int q4 = lane >> 4, l16 = lane & 15;
    const int bh = blockIdx.x;
    const int b = bh >> 3, h = bh & 7;
    const int w = b & 511;
    const long base = (long)bh * 98 * 32;

    for (int idx = tid; idx < 448; idx += 256) {
        int n = idx >> 2, dg = (idx & 3) * 8;
        uint4 val = make_uint4(0, 0, 0, 0);
        if (n < 98) val = *reinterpret_cast<const uint4*>(q + base + n * 32 + dg);
        *reinterpret_cast<uint4*>(&Qs[n * 40 + dg]) = val;
    }
    for (int idx = tid; idx < 448; idx += 256) {
        int n = idx >> 2, dg = (idx & 3) * 8;
        uint4 val = make_uint4(0, 0, 0, 0);
        if (n < 98) val = *reinterpret_cast<const uint4*>(k + base + n * 32 + dg);
        *reinterpret_cast<uint4*>(&Ks[n * 40 + dg]) = val;
    }
    for (int idx = tid; idx < 392; idx += 256) {
        int m = idx >> 2, dg = (idx & 3) * 8;
        uint4 u = *reinterpret_cast<const uint4*>(v + base + m * 32 + dg);
        const unsigned short* us = reinterpret_cast<const unsigned short*>(&u);
#pragma unroll
        for (int j = 0; j < 8; ++j) Vt[(dg + j) * 136 + m] = us[j];
    }
    for (int idx = tid; idx < 960; idx += 256) {   // zero Vt m in [98,128)
        int d = idx / 30, m = 98 + idx - d * 30;
        Vt[d * 136 + m] = 0;
    }
    for (int idx = tid; idx < 1792; idx += 256) {  // zero P cols [112,128)
        int n = idx >> 4, m = 112 + (idx & 15);
        P[n * 136 + m] = 0;
    }
    __syncthreads();

    const float scale = 0.17677669529663687f;  // 1/sqrt(32)
    const float* maskp = mask + (long)w * 9604;
    const float* biasp = bias_full + (long)h * 9604;

    // QK^T + softmax: wave owns row-bands tr = wave, wave+4
    for (int tr = wave; tr < 7; tr += 4) {
        short8 a = *reinterpret_cast<const short8*>(&Qs[(tr * 16 + l16) * 40 + q4 * 8]);
        f32x4 val[7];
#pragma unroll
        for (int tc = 0; tc < 7; ++tc) {
            short8 bb = *reinterpret_cast<const short8*>(&Ks[(tc * 16 + l16) * 40 + q4 * 8]);
            f32x4 d = (f32x4){0.f, 0.f, 0.f, 0.f};
            d = __builtin_amdgcn_mfma_f32_16x16x32_bf16(a, bb, d, 0, 0, 0);
            int m = tc * 16 + l16;
            f32x4 o;
#pragma unroll
            for (int r = 0; r < 4; ++r) {
                int n = tr * 16 + q4 * 4 + r;
                float x = -1e30f;
                if (n < 98 && m < 98)
                    x = d[r] * scale + biasp[n * 98 + m] + maskp[n * 98 + m];
                o[r] = x;
            }
            val[tc] = o;
        }
        float rinv[4];
#pragma unroll
        for (int r = 0; r < 4; ++r) {
            float mx = val[0][r];
#pragma unroll
            for (int tc = 1; tc < 7; ++tc) mx = fmaxf(mx, val[tc][r]);
#pragma unroll
            for (int off = 1; off < 16; off <<= 1) mx = fmaxf(mx, __shfl_xor(mx, off, 16));
            float sm = 0.f;
#pragma unroll
            for (int tc = 0; tc < 7; ++tc) {
                float e = __expf(val[tc][r] - mx);
                val[tc][r] = e;
                sm += e;
            }
#pragma unroll
            for (int off = 1; off < 16; off <<= 1) sm += __shfl_xor(sm, off, 16);
            rinv[r] = 1.f / sm;
        }
#pragma unroll
        for (int tc = 0; tc < 7; ++tc) {
            int m = tc * 16 + l16;
#pragma unroll
            for (int r = 0; r < 4; ++r) {
                int n = tr * 16 + q4 * 4 + r;
                P[n * 136 + m] = f2bf(val[tc][r] * rinv[r]);
            }
        }
    }
    __syncthreads();

    // O = P V : 7x2 tiles
    const long obase = (long)b * 98 * 256 + h * 32;
    for (int t = wave; t < 14; t += 4) {
        int tr = t >> 1, tc = t & 1;
        f32x4 o = (f32x4){0.f, 0.f, 0.f, 0.f};
#pragma unroll
        for (int kc = 0; kc < 4; ++kc) {
            short8 a = *reinterpret_cast<const short8*>(&P[(tr * 16 + l16) * 136 + kc * 32 + q4 * 8]);
            short8 bb = *reinterpret_cast<const short8*>(&Vt[(tc * 16 + l16) * 136 + kc * 32 + q4 * 8]);
            o = __builtin_amdgcn_mfma_f32_16x16x32_bf16(a, bb, o, 0, 0, 0);
        }
        int d = tc * 16 + l16;
#pragma unroll
        for (int r = 0; r < 4; ++r) {
            int n = tr * 16 + q4 * 4 + r;
            if (n < 98) attn_out[obase + n * 256 + d] = f2bf(o[r]);
        }
    }
}

// ---------------------------------------------------------------- proj GEMM
__global__ __launch_bounds__(256, 2)
void gemm_proj_kernel(const unsigned short* __restrict__ Abf,  // (M,256) bf16
                      const float* __restrict__ W,             // (256,256)
                      const float* __restrict__ bias,
                      float* __restrict__ out) {
    __shared__ unsigned short As[128 * LDSK];
    __shared__ unsigned short Bs[128 * LDSK];
    const int tid = threadIdx.x;
    const int wave = tid >> 6, lane = tid & 63;
    const int q4 = lane >> 4, l16 = lane & 15;
    const int wr = wave >> 1, wc = wave & 1;
    const long m0 = (long)blockIdx.y * 128;
    const int n0 = blockIdx.x * 128;

    f32x4 acc[4][4];
#pragma unroll
    for (int i = 0; i < 4; ++i)
#pragma unroll
        for (int j = 0; j < 4; ++j) acc[i][j] = (f32x4){0.f, 0.f, 0.f, 0.f};

    for (int ks = 0; ks < 256; ks += 64) {
#pragma unroll
        for (int it = 0; it < 4; ++it) {
            int e = (it * 256 + tid) * 8;
            int m = e >> 6, k = e & 63;
            uint4 u = *reinterpret_cast<const uint4*>(Abf + (m0 + m) * 256 + ks + k);
            *reinterpret_cast<uint4*>(&As[m * LDSK + k]) = u;
        }
#pragma unroll
        for (int it = 0; it < 8; ++it) {
            int e = (it * 256 + tid) * 4;
            int n = e >> 6, k = e & 63;
            float4 f = *reinterpret_cast<const float4*>(W + (long)(n0 + n) * 256 + ks + k);
            unsigned int lo = ((unsigned)f2bf(f.y) << 16) | f2bf(f.x);
            unsigned int hi = ((unsigned)f2bf(f.w) << 16) | f2bf(f.z);
            *reinterpret_cast<uint2*>(&Bs[n * LDSK + k]) = make_uint2(lo, hi);
        }
        __syncthreads();
#pragma unroll
        for (int s = 0; s < 2; ++s) {
            short8 a[4], b[4];
#pragma unroll
            for (int i = 0; i < 4; ++i)
                a[i] = *reinterpret_cast<const short8*>(&As[(wr * 64 + i * 16 + l16) * LDSK + s * 32 + q4 * 8]);
#pragma unroll
            for (int j = 0; j < 4; ++j)
                b[j] = *reinterpret_cast<const short8*>(&Bs[(wc * 64 + j * 16 + l16) * LDSK + s * 32 + q4 * 8]);
#pragma unroll
            for (int i = 0; i < 4; ++i)
#pragma unroll
                for (int j = 0; j < 4; ++j)
                    acc[i][j] = __builtin_amdgcn_mfma_f32_16x16x32_bf16(a[i], b[j], acc[i][j], 0, 0, 0);
        }
        __syncthreads();
    }
#pragma unroll
    for (int i = 0; i < 4; ++i) {
#pragma unroll
        for (int r = 0; r < 4; ++r) {
            long row = m0 + wr * 64 + i * 16 + q4 * 4 + r;
#pragma unroll
            for (int j = 0; j < 4; ++j) {
                int col = n0 + wc * 64 + j * 16 + l16;
                out[row * 256 + col] = acc[i][j][r] + bias[col];
            }
        }
    }
}

// ---------------------------------------------------------------- launch
extern "C" void kernel_launch(void* const* d_in, const int* in_sizes, int n_in,
                              void* d_out, int out_size, void* d_ws, size_t ws_size,
                              hipStream_t stream) {
    (void)in_sizes; (void)n_in; (void)out_size; (void)ws_size;
    const float* x          = (const float*)d_in[0];
    const float* mask       = (const float*)d_in[1];
    const float* qkv_w      = (const float*)d_in[2];
    const float* qkv_b      = (const float*)d_in[3];
    const float* proj_w     = (const float*)d_in[4];
    const float* proj_b     = (const float*)d_in[5];
    const float* bias_table = (const float*)d_in[6];
    const int*   rel_index  = (const int*)d_in[7];
    float* out = (float*)d_out;

    const long QN = 51380224;  // 2048*8*98*32 elements (bf16)
    unsigned short* qws = (unsigned short*)d_ws;
    unsigned short* kws = qws + QN;
    unsigned short* vws = kws + QN;
    unsigned short* aow = vws + QN;             // attn_out (M,256) bf16
    float* bias_full = (float*)(aow + QN);      // 8*9604 fp32

    bias_expand_kernel<<<dim3((8 * 9604 + 255) / 256), dim3(256), 0, stream>>>(
        bias_table, rel_index, bias_full);
    gemm_qkv_kernel<<<dim3(6, 1568), dim3(256), 0, stream>>>(
        x, qkv_w, qkv_b, qws, kws, vws);
    attn_kernel<<<dim3(16384), dim3(256), 0, stream>>>(
        qws, kws, vws, mask, bias_full, aow);
    gemm_proj_kernel<<<dim3(2, 1568), dim3(256), 0, stream>>>(
        aow, proj_w, proj_b, out);
}

// Round 2
// 1202.245 us; speedup vs baseline: 1.2542x; 1.2542x over previous
//
#include <hip/hip_runtime.h>
#include <hip/hip_bf16.h>

typedef __attribute__((ext_vector_type(8))) short short8;
typedef __attribute__((ext_vector_type(4))) float f32x4;

__device__ __forceinline__ unsigned short f2bf(float f) {
    __hip_bfloat16 h = __float2bfloat16(f);
    union { __hip_bfloat16 h; unsigned short u; } c; c.h = h; return c.u;
}

// ---------------------------------------------------------------- bias expand
// bias_full[h*9604 + n*98 + m] = bias_table[rel_index[n*98+m]*8 + h]
__global__ void bias_expand_kernel(const float* __restrict__ bias_table,
                                   const int* __restrict__ rel_index,
                                   float* __restrict__ bias_full) {
    int idx = blockIdx.x * 256 + threadIdx.x;
    if (idx >= 8 * 9604) return;
    int h = idx / 9604;
    int r = idx - h * 9604;
    bias_full[idx] = bias_table[rel_index[r] * 8 + h];
}

// ---------------------------------------------------------------- vt pad zero
// zero vtws[bhd][98..112) so attn can vector-load padded rows
__global__ void vt_zerofill_kernel(unsigned short* __restrict__ vtws) {
    int idx = blockIdx.x * 256 + threadIdx.x;  // 16384*32*7 uint writes
    if (idx >= 16384 * 32 * 7) return;
    int bhd = idx / 7, j = idx - bhd * 7;
    unsigned* p = reinterpret_cast<unsigned*>(vtws + (long)bhd * 112 + 98);
    p[j] = 0;
}

// ---------------------------------------------------------------- QKV GEMM
#define LDSK 72  // 64 + 8 pad (bf16) -> 144B row stride, 2-way bank alias (free)

__global__ __launch_bounds__(256, 2)
void gemm_qkv_kernel(const float* __restrict__ X,
                     const float* __restrict__ W,
                     const float* __restrict__ bias,
                     unsigned short* __restrict__ qws,
                     unsigned short* __restrict__ kws,
                     unsigned short* __restrict__ vtws) {
    __shared__ unsigned short As[128 * LDSK];
    __shared__ unsigned short Bs[128 * LDSK];
    const int tid = threadIdx.x;
    const int wave = tid >> 6, lane = tid & 63;
    const int q4 = lane >> 4, l16 = lane & 15;
    const int wr = wave >> 1, wc = wave & 1;
    const long m0 = (long)blockIdx.y * 128;
    const int n0 = blockIdx.x * 128;

    f32x4 acc[4][4];
#pragma unroll
    for (int i = 0; i < 4; ++i)
#pragma unroll
        for (int j = 0; j < 4; ++j) acc[i][j] = (f32x4){0.f, 0.f, 0.f, 0.f};

    for (int ks = 0; ks < 256; ks += 64) {
#pragma unroll
        for (int it = 0; it < 8; ++it) {
            int e = (it * 256 + tid) * 4;
            int m = e >> 6, k = e & 63;
            float4 f = *reinterpret_cast<const float4*>(X + (m0 + m) * 256 + ks + k);
            unsigned int lo = ((unsigned)f2bf(f.y) << 16) | f2bf(f.x);
            unsigned int hi = ((unsigned)f2bf(f.w) << 16) | f2bf(f.z);
            *reinterpret_cast<uint2*>(&As[m * LDSK + k]) = make_uint2(lo, hi);
        }
#pragma unroll
        for (int it = 0; it < 8; ++it) {
            int e = (it * 256 + tid) * 4;
            int n = e >> 6, k = e & 63;
            float4 f = *reinterpret_cast<const float4*>(W + (long)(n0 + n) * 256 + ks + k);
            unsigned int lo = ((unsigned)f2bf(f.y) << 16) | f2bf(f.x);
            unsigned int hi = ((unsigned)f2bf(f.w) << 16) | f2bf(f.z);
            *reinterpret_cast<uint2*>(&Bs[n * LDSK + k]) = make_uint2(lo, hi);
        }
        __syncthreads();
#pragma unroll
        for (int s = 0; s < 2; ++s) {
            short8 a[4], b[4];
#pragma unroll
            for (int i = 0; i < 4; ++i)
                a[i] = *reinterpret_cast<const short8*>(&As[(wr * 64 + i * 16 + l16) * LDSK + s * 32 + q4 * 8]);
#pragma unroll
            for (int j = 0; j < 4; ++j)
                b[j] = *reinterpret_cast<const short8*>(&Bs[(wc * 64 + j * 16 + l16) * LDSK + s * 32 + q4 * 8]);
#pragma unroll
            for (int i = 0; i < 4; ++i)
#pragma unroll
                for (int j = 0; j < 4; ++j)
                    acc[i][j] = __builtin_amdgcn_mfma_f32_16x16x32_bf16(a[i], b[j], acc[i][j], 0, 0, 0);
        }
        __syncthreads();
    }
    // epilogue: scatter per-head; V goes out transposed (bh, d, 112)
#pragma unroll
    for (int i = 0; i < 4; ++i) {
#pragma unroll
        for (int r = 0; r < 4; ++r) {
            long row = m0 + wr * 64 + i * 16 + q4 * 4 + r;
            int b_ = (int)(row / 98);
            int n_ = (int)(row - (long)b_ * 98);
#pragma unroll
            for (int j = 0; j < 4; ++j) {
                int col = n0 + wc * 64 + j * 16 + l16;
                float vv = acc[i][j][r] + bias[col];
                int which = col >> 8;
                int h = (col >> 5) & 7;
                int d = col & 31;
                if (which == 2) {
                    vtws[((long)(b_ * 8 + h) * 32 + d) * 112 + n_] = f2bf(vv);
                } else {
                    unsigned short* dst = which ? kws : qws;
                    dst[((long)(b_ * 8 + h) * 98 + n_) * 32 + d] = f2bf(vv);
                }
            }
        }
    }
}

// ---------------------------------------------------------------- attention
// one block (256 thr) per (b,h). S^T via mfma(A=K,B=Q); P stays in registers,
// transformed to PV A-operand layout with cross-quad shuffles (no P LDS).
__global__ __launch_bounds__(256, 4)
void attn_kernel(const unsigned short* __restrict__ q,
                 const unsigned short* __restrict__ k,
                 const unsigned short* __restrict__ vt,   // (bh,32,112)
                 const float* __restrict__ mask,          // (512,98,98)
                 const float* __restrict__ bias_full,     // (8,98,98)
                 unsigned short* __restrict__ attn_out) {
    __shared__ unsigned short Qs[112 * 40];   // 8960 B
    __shared__ unsigned short Ks[112 * 40];   // 8960 B
    __shared__ unsigned short Vt[32 * 136];   // 8704 B (cols 0..127 used)

    const int tid = threadIdx.x;
    const int wave = tid >> 6, lane = tid & 63;
    const int q4 = lane >> 4, l16 = lane & 15;
    const int bh = blockIdx.x;
    const int b = bh >> 3, h = bh & 7;
    const int w = b & 511;
    const long base = (long)bh * 98 * 32;

    for (int idx = tid; idx < 448; idx += 256) {
        int n = idx >> 2, dg = (idx & 3) * 8;
        uint4 val = make_uint4(0, 0, 0, 0);
        if (n < 98) val = *reinterpret_cast<const uint4*>(q + base + n * 32 + dg);
        *reinterpret_cast<uint4*>(&Qs[n * 40 + dg]) = val;
    }
    for (int idx = tid; idx < 448; idx += 256) {
        int n = idx >> 2, dg = (idx & 3) * 8;
        uint4 val = make_uint4(0, 0, 0, 0);
        if (n < 98) val = *reinterpret_cast<const uint4*>(k + base + n * 32 + dg);
        *reinterpret_cast<uint4*>(&Ks[n * 40 + dg]) = val;
    }
    const unsigned short* vtp = vt + (long)bh * 3584;
    for (int idx = tid; idx < 448; idx += 256) {
        int d = idx / 14, ch = idx - d * 14;
        *reinterpret_cast<uint4*>(&Vt[d * 136 + ch * 8]) =
            *reinterpret_cast<const uint4*>(vtp + d * 112 + ch * 8);
    }
    if (tid < 64) {  // zero Vt cols [112,128)
        int d = tid >> 1, c = tid & 1;
        *reinterpret_cast<uint4*>(&Vt[d * 136 + 112 + c * 8]) = make_uint4(0, 0, 0, 0);
    }
    __syncthreads();

    const float scale = 0.17677669529663687f;  // 1/sqrt(32)
    const float* maskp = mask + (long)w * 9604;
    const float* biasp = bias_full + (long)h * 9604;
    const long obase = (long)b * 98 * 256 + h * 32;

    for (int tr = wave; tr < 7; tr += 4) {
        const int n = tr * 16 + l16;           // this lane's query index
        short8 bq = *reinterpret_cast<const short8*>(&Qs[(tr * 16 + l16) * 40 + q4 * 8]);
        f32x4 pv[7];
#pragma unroll
        for (int i = 0; i < 7; ++i) {
            short8 ak = *reinterpret_cast<const short8*>(&Ks[(i * 16 + l16) * 40 + q4 * 8]);
            f32x4 d = (f32x4){0.f, 0.f, 0.f, 0.f};
            d = __builtin_amdgcn_mfma_f32_16x16x32_bf16(ak, bq, d, 0, 0, 0);
            // d[r] = S[n][m], m = i*16 + q4*4 + r
            int m0 = i * 16 + q4 * 4;
            f32x4 o;
            if (n < 98 && m0 + 3 < 98) {
                float2 mk0 = *reinterpret_cast<const float2*>(maskp + n * 98 + m0);
                float2 mk1 = *reinterpret_cast<const float2*>(maskp + n * 98 + m0 + 2);
                float2 bb0 = *reinterpret_cast<const float2*>(biasp + n * 98 + m0);
                float2 bb1 = *reinterpret_cast<const float2*>(biasp + n * 98 + m0 + 2);
                o[0] = d[0] * scale + mk0.x + bb0.x;
                o[1] = d[1] * scale + mk0.y + bb0.y;
                o[2] = d[2] * scale + mk1.x + bb1.x;
                o[3] = d[3] * scale + mk1.y + bb1.y;
            } else {
#pragma unroll
                for (int r = 0; r < 4; ++r) {
                    int m = m0 + r;
                    o[r] = (n < 98 && m < 98)
                         ? d[r] * scale + maskp[n * 98 + m] + biasp[n * 98 + m]
                         : -1e30f;
                }
            }
            pv[i] = o;
        }
        // softmax over m (in-lane 28 values, then cross-quad lanes l16+{16,32,48})
        float mx = -1e30f;
#pragma unroll
        for (int i = 0; i < 7; ++i)
#pragma unroll
            for (int r = 0; r < 4; ++r) mx = fmaxf(mx, pv[i][r]);
        mx = fmaxf(mx, __shfl_xor(mx, 16));
        mx = fmaxf(mx, __shfl_xor(mx, 32));
        float sm = 0.f;
#pragma unroll
        for (int i = 0; i < 7; ++i)
#pragma unroll
            for (int r = 0; r < 4; ++r) {
                float e = __expf(pv[i][r] - mx);
                pv[i][r] = e;
                sm += e;
            }
        sm += __shfl_xor(sm, 16);
        sm += __shfl_xor(sm, 32);
        float rinv = 1.f / sm;
        // pack normalized P as bf16 pairs
        unsigned up[8][2];
#pragma unroll
        for (int i = 0; i < 7; ++i) {
            up[i][0] = ((unsigned)f2bf(pv[i][1] * rinv) << 16) | f2bf(pv[i][0] * rinv);
            up[i][1] = ((unsigned)f2bf(pv[i][3] * rinv) << 16) | f2bf(pv[i][2] * rinv);
        }
        up[7][0] = 0; up[7][1] = 0;
        // PV: shuffle P into A-operand layout, accumulate over kc
        f32x4 o0 = (f32x4){0.f, 0.f, 0.f, 0.f};
        f32x4 o1 = (f32x4){0.f, 0.f, 0.f, 0.f};
        const int srcA = ((q4 & 1) * 2) * 16 + l16;
        const int srcB = srcA + 16;
        const bool hi = (q4 >= 2);
#pragma unroll
        for (int kc = 0; kc < 4; ++kc) {
            int ie = 2 * kc, io = 2 * kc + 1;
            unsigned a0e = __shfl(up[ie][0], srcA), a0o = __shfl(up[io][0], srcA);
            unsigned a1e = __shfl(up[ie][1], srcA), a1o = __shfl(up[io][1], srcA);
            unsigned b0e = __shfl(up[ie][0], srcB), b0o = __shfl(up[io][0], srcB);
            unsigned b1e = __shfl(up[ie][1], srcB), b1o = __shfl(up[io][1], srcB);
            union { uint4 u; short8 s; } cvt;
            cvt.u.x = hi ? a0o : a0e;
            cvt.u.y = hi ? a1o : a1e;
            cvt.u.z = hi ? b0o : b0e;
            cvt.u.w = hi ? b1o : b1e;
            short8 bv0 = *reinterpret_cast<const short8*>(&Vt[l16 * 136 + kc * 32 + q4 * 8]);
            short8 bv1 = *reinterpret_cast<const short8*>(&Vt[(16 + l16) * 136 + kc * 32 + q4 * 8]);
            o0 = __builtin_amdgcn_mfma_f32_16x16x32_bf16(cvt.s, bv0, o0, 0, 0, 0);
            o1 = __builtin_amdgcn_mfma_f32_16x16x32_bf16(cvt.s, bv1, o1, 0, 0, 0);
        }
        // store: row n' = tr*16 + q4*4 + r, cols d = l16 and 16+l16
#pragma unroll
        for (int r = 0; r < 4; ++r) {
            int nn = tr * 16 + q4 * 4 + r;
            if (nn < 98) {
                attn_out[obase + nn * 256 + l16] = f2bf(o0[r]);
                attn_out[obase + nn * 256 + 16 + l16] = f2bf(o1[r]);
            }
        }
    }
}

// ---------------------------------------------------------------- proj GEMM
__global__ __launch_bounds__(256, 2)
void gemm_proj_kernel(const unsigned short* __restrict__ Abf,  // (M,256) bf16
                      const float* __restrict__ W,             // (256,256)
                      const float* __restrict__ bias,
                      float* __restrict__ out) {
    __shared__ unsigned short As[128 * LDSK];
    __shared__ unsigned short Bs[128 * LDSK];
    const int tid = threadIdx.x;
    const int wave = tid >> 6, lane = tid & 63;
    const int q4 = lane >> 4, l16 = lane & 15;
    const int wr = wave >> 1, wc = wave & 1;
    const long m0 = (long)blockIdx.y * 128;
    const int n0 = blockIdx.x * 128;

    f32x4 acc[4][4];
#pragma unroll
    for (int i = 0; i < 4; ++i)
#pragma unroll
        for (int j = 0; j < 4; ++j) acc[i][j] = (f32x4){0.f, 0.f, 0.f, 0.f};

    for (int ks = 0; ks < 256; ks += 64) {
#pragma unroll
        for (int it = 0; it < 4; ++it) {
            int e = (it * 256 + tid) * 8;
            int m = e >> 6, k = e & 63;
            uint4 u = *reinterpret_cast<const uint4*>(Abf + (m0 + m) * 256 + ks + k);
            *reinterpret_cast<uint4*>(&As[m * LDSK + k]) = u;
        }
#pragma unroll
        for (int it = 0; it < 8; ++it) {
            int e = (it * 256 + tid) * 4;
            int n = e >> 6, k = e & 63;
            float4 f = *reinterpret_cast<const float4*>(W + (long)(n0 + n) * 256 + ks + k);
            unsigned int lo = ((unsigned)f2bf(f.y) << 16) | f2bf(f.x);
            unsigned int hi = ((unsigned)f2bf(f.w) << 16) | f2bf(f.z);
            *reinterpret_cast<uint2*>(&Bs[n * LDSK + k]) = make_uint2(lo, hi);
        }
        __syncthreads();
#pragma unroll
        for (int s = 0; s < 2; ++s) {
            short8 a[4], b[4];
#pragma unroll
            for (int i = 0; i < 4; ++i)
                a[i] = *reinterpret_cast<const short8*>(&As[(wr * 64 + i * 16 + l16) * LDSK + s * 32 + q4 * 8]);
#pragma unroll
            for (int j = 0; j < 4; ++j)
                b[j] = *reinterpret_cast<const short8*>(&Bs[(wc * 64 + j * 16 + l16) * LDSK + s * 32 + q4 * 8]);
#pragma unroll
            for (int i = 0; i < 4; ++i)
#pragma unroll
                for (int j = 0; j < 4; ++j)
                    acc[i][j] = __builtin_amdgcn_mfma_f32_16x16x32_bf16(a[i], b[j], acc[i][j], 0, 0, 0);
        }
        __syncthreads();
    }
#pragma unroll
    for (int i = 0; i < 4; ++i) {
#pragma unroll
        for (int r = 0; r < 4; ++r) {
            long row = m0 + wr * 64 + i * 16 + q4 * 4 + r;
#pragma unroll
            for (int j = 0; j < 4; ++j) {
                int col = n0 + wc * 64 + j * 16 + l16;
                out[row * 256 + col] = acc[i][j][r] + bias[col];
            }
        }
    }
}

// ---------------------------------------------------------------- launch
extern "C" void kernel_launch(void* const* d_in, const int* in_sizes, int n_in,
                              void* d_out, int out_size, void* d_ws, size_t ws_size,
                              hipStream_t stream) {
    (void)in_sizes; (void)n_in; (void)out_size; (void)ws_size;
    const float* x          = (const float*)d_in[0];
    const float* mask       = (const float*)d_in[1];
    const float* qkv_w      = (const float*)d_in[2];
    const float* qkv_b      = (const float*)d_in[3];
    const float* proj_w     = (const float*)d_in[4];
    const float* proj_b     = (const float*)d_in[5];
    const float* bias_table = (const float*)d_in[6];
    const int*   rel_index  = (const int*)d_in[7];
    float* out = (float*)d_out;

    const long QN = 51380224;   // 2048*8*98*32 (bf16 elems)
    const long VT = 58720256;   // 2048*8*32*112 (bf16 elems)
    unsigned short* qws  = (unsigned short*)d_ws;
    unsigned short* kws  = qws + QN;
    unsigned short* vtws = kws + QN;
    unsigned short* aow  = vtws + VT;           // attn_out (M,256) bf16
    float* bias_full = (float*)(aow + QN);      // 8*9604 fp32

    vt_zerofill_kernel<<<dim3((16384 * 32 * 7 + 255) / 256), dim3(256), 0, stream>>>(vtws);
    bias_expand_kernel<<<dim3((8 * 9604 + 255) / 256), dim3(256), 0, stream>>>(
        bias_table, rel_index, bias_full);
    gemm_qkv_kernel<<<dim3(6, 1568), dim3(256), 0, stream>>>(
        x, qkv_w, qkv_b, qws, kws, vtws);
    attn_kernel<<<dim3(16384), dim3(256), 0, stream>>>(
        qws, kws, vtws, mask, bias_full, aow);
    gemm_proj_kernel<<<dim3(2, 1568), dim3(256), 0, stream>>>(
        aow, proj_w, proj_b, out);
}